// Round 1
// 211.956 us; speedup vs baseline: 1.0121x; 1.0121x over previous
//
#include <hip/hip_runtime.h>
#include <hip/hip_bf16.h>
#include <cstddef>

// ---------------------------------------------------------------------------
// AttentionBlock: B=2, H=W=64 (S=4096), C=512, GROUPS=32, fp32 in/out.
// GroupNorm -> qkv -> P = softmax(q k^T / sqrt(C)) -> o = P v -> o@Wp + bp + x
// R8: persistent single kernel with MANUAL grid barrier (normal launch ->
//     graph-capturable). Grid = 1024 = 4 blocks/CU, co-residency enforced by
//     __launch_bounds__(256,4) + 32KB LDS and guarded by a host occupancy
//     query (fallback = proven R5 schedule).
// R9: XCD-locality tile remap. rocprof showed MfmaUtil ~17% (real-run) vs the
//     37% this GEMM structure sustains standalone; HBM traffic is compulsory
//     (154+144 MB) -> the stall is L3-latency on tile-amplified staging
//     (P x8, q/k strips x32, o2 x8, xn x12 ~= 1.1 GB through L3). Old maps
//     scattered strip-sharing tiles across XCDs (round-robin dispatch) so the
//     per-XCD 4MB L2 saw zero reuse. New bijective maps chunk tiles so
//     sharers are co-resident on one XCD: ph3 8Mx12N/XCD (2.5MB), ph4 4 q-rows
//     x 32 k-cols/XCD, ph5 P-strip-grouped (8 N-tiles of one 0.5MB strip on 8
//     adjacent blocks), ph6 8Mx8N/XCD (2.5MB).
// ---------------------------------------------------------------------------

typedef __bf16 bf16;
typedef __attribute__((ext_vector_type(8))) __bf16 bf16x8;
typedef __attribute__((ext_vector_type(4))) __bf16 bf16x4;
typedef __attribute__((ext_vector_type(4))) float f32x4;

#define SEQ   4096
#define CCH   512
#define NBAT  2
#define NOMASK 0x7FFFFFFF
#define SMEM_BYTES 32768   // As 16K + Bs 16K; EPI2 reduce reuses As post-loop
#define PGRID 1024         // persistent grid: 4 blocks/CU x 256 CUs

// ---------------------------------------------------------------------------
// Manual grid barrier. bar[idx] zeroed by hipMemsetAsync before launch.
// All PGRID blocks must call with the same idx.
__device__ __forceinline__ void grid_bar(unsigned* bar, int idx) {
    __syncthreads();                          // block done with phase work
    if (threadIdx.x == 0) {
        __threadfence();                      // agent-scope release
        __hip_atomic_fetch_add(&bar[idx], 1u, __ATOMIC_RELEASE,
                               __HIP_MEMORY_SCOPE_AGENT);
        while (__hip_atomic_load(&bar[idx], __ATOMIC_RELAXED,
                                 __HIP_MEMORY_SCOPE_AGENT) < (unsigned)PGRID)
            __builtin_amdgcn_s_sleep(1);
        __threadfence();                      // agent-scope acquire
    }
    __syncthreads();                          // release remaining waves
}

// ---------------------------------------------------------------------------
// prep unit: bid<512 GN-stats partials (statsP[bg*16+c]=S, +8+c=SS, race-free)
//            bid in [512,1536) weight transpose-cast; bid==1536 bias pack.
__device__ __forceinline__ void prep_unit(
    char* smem, int bid, const float* __restrict__ x,
    const float* __restrict__ Wq, const float* __restrict__ Wk,
    const float* __restrict__ Wv, const float* __restrict__ Wp,
    const float* __restrict__ bq, const float* __restrict__ bk,
    const float* __restrict__ bv,
    float* __restrict__ statsP, bf16* __restrict__ WqkvT,
    bf16* __restrict__ WpT, float* __restrict__ biasQKV) {
    const int tid = threadIdx.x;
    if (bid < 512) {
        float* red = (float*)smem;            // 8 floats
        int bg = bid >> 3, c = bid & 7;
        int b = bg >> 5, g = bg & 31;
        const float* base = x + (size_t)b * SEQ * CCH + g * 16;
        float s = 0.f, ss = 0.f;
        for (int i = tid; i < 2048; i += 256) {      // 512 spatial x 4 float4
            int sp = c * 512 + (i >> 2), q = i & 3;
            float4 v = *(const float4*)(base + (size_t)sp * CCH + q * 4);
            s  += v.x + v.y + v.z + v.w;
            ss += v.x * v.x + v.y * v.y + v.z * v.z + v.w * v.w;
        }
        #pragma unroll
        for (int o = 32; o > 0; o >>= 1) { s += __shfl_down(s, o); ss += __shfl_down(ss, o); }
        int wave = tid >> 6, lane = tid & 63;
        if (lane == 0) { red[wave] = s; red[4 + wave] = ss; }
        __syncthreads();
        if (tid == 0) {
            statsP[bg * 16 + c]     = red[0] + red[1] + red[2] + red[3];
            statsP[bg * 16 + 8 + c] = red[4] + red[5] + red[6] + red[7];
        }
        __syncthreads();
    } else if (bid < 1536) {
        float (*tile)[33] = (float(*)[33])smem;      // 4224 B
        int w = bid - 512;
        int z = w >> 8, rest = w & 255;
        int k0 = (rest >> 4) * 32, n0 = (rest & 15) * 32;
        const float* W = (z == 0) ? Wq : (z == 1) ? Wk : (z == 2) ? Wv : Wp;
        int tx = tid & 31, ty = tid >> 5;
        #pragma unroll
        for (int i = ty; i < 32; i += 8)
            tile[i][tx] = W[(size_t)(k0 + i) * CCH + n0 + tx];
        __syncthreads();
        bf16* dst = (z < 3) ? (WqkvT + (size_t)z * CCH * CCH) : WpT;
        #pragma unroll
        for (int i = ty; i < 32; i += 8)
            dst[(size_t)(n0 + i) * CCH + k0 + tx] = (bf16)tile[tx][i];
        __syncthreads();
    } else {
        for (int i = tid; i < 1536; i += 256) {
            float v = (i < 512) ? bq[i] : (i < 1024) ? bk[i - 512] : bv[i - 1024];
            biasQKV[i] = v;
        }
    }
}

// Build per-block (mu, rstd) table for the 64 (b,g) groups from partials.
__device__ __forceinline__ void gn_table(char* smem, const float* __restrict__ statsP) {
    float* tbl = (float*)smem;                // 128 floats
    const int tid = threadIdx.x;
    if (tid < 64) {
        float S = 0.f, SS = 0.f;
        #pragma unroll
        for (int c = 0; c < 8; ++c) { S += statsP[tid * 16 + c]; SS += statsP[tid * 16 + 8 + c]; }
        float mu = S * (1.f / 65536.f);
        float rs = rsqrtf(SS * (1.f / 65536.f) - mu * mu + 1e-5f);
        tbl[tid * 2] = mu; tbl[tid * 2 + 1] = rs;
    }
    __syncthreads();
}

// gn unit: one 256-thread block's worth (256 float4 of [8192][128]).
__device__ __forceinline__ void gn_unit(
    char* smem, int w, const float* __restrict__ x,
    const float* __restrict__ gamma, const float* __restrict__ beta,
    bf16* __restrict__ xn) {
    const float* tbl = (const float*)smem;
    size_t idx = (size_t)w * 256 + threadIdx.x;
    int c4 = (int)(idx & 127);
    int b = (int)(idx >> 19);
    int bg = b * 32 + (c4 >> 2);
    float mu = tbl[bg * 2], rs = tbl[bg * 2 + 1];
    float4 v  = ((const float4*)x)[idx];
    float4 gm = ((const float4*)gamma)[c4];
    float4 bt = ((const float4*)beta)[c4];
    bf16x4 o;
    o[0] = (bf16)((v.x - mu) * rs * gm.x + bt.x);
    o[1] = (bf16)((v.y - mu) * rs * gm.y + bt.y);
    o[2] = (bf16)((v.z - mu) * rs * gm.z + bt.z);
    o[3] = (bf16)((v.w - mu) * rs * gm.w + bt.w);
    ((bf16x4*)xn)[idx] = o;
}

// vtrans unit: 64x64 transpose of qkv's v slice -> vT[b][c][s].
__device__ __forceinline__ void vtrans_unit(char* smem,
                                            const bf16* __restrict__ qkv,
                                            bf16* __restrict__ vT,
                                            int b, int s0, int c0) {
    bf16 (*tile)[65] = (bf16(*)[65])smem;     // 8320 B
    const int tx = threadIdx.x & 63;
    const int w = threadIdx.x >> 6;
    #pragma unroll
    for (int i = 0; i < 16; ++i) {
        int row = w + i * 4;
        tile[row][tx] = qkv[((size_t)b * SEQ + s0 + row) * 1536 + 1024 + c0 + tx];
    }
    __syncthreads();
    #pragma unroll
    for (int i = 0; i < 16; ++i) {
        int row = w + i * 4;
        vT[((size_t)b * CCH + c0 + row) * SEQ + s0 + tx] = tile[tx][row];
    }
    __syncthreads();
}

// ---------------------------------------------------------------------------
// Generalized bf16 B^T GEMM body (R4/R5 core): 128 x BN tile, BK=64, async
// global->LDS (16B), XOR-swizzled LDS (chunk ^= row&7), 16x16x32 MFMA.
//   C[m][n] = sum_k A[m][k] * Bt[n][k & bkmask]
// Epilogues: 0 bf16=acc+bias[n] | 1 bf16=exp(acc*scale)+lsum partials |
//            2 bf16=acc/l (l reduced post-K-loop in dead As space;
//              split-K=2 via bz) | 3 f32=acc+bias[n]+resid[m*512+n]
template <int EPI, int BN>
__device__ __forceinline__ void gemm2_body(
    char* smem, int bxi, int byi, int bzi,
    const bf16* __restrict__ A, long long aBatch, int lda,
    const bf16* __restrict__ Bt, long long bBatch, int ldb,
    void* __restrict__ Cout, long long cBatch, int ldc,
    int K, int bkmask, float scale,
    const float* __restrict__ bias, const float* __restrict__ resid,
    float* __restrict__ lsum, long long lsumBatch) {
    constexpr int JN = BN / 32;
    bf16* As = (bf16*)smem;                       // 16384 B
    bf16* Bs = (bf16*)(smem + 16384);             // up to 16384 B
    const int tid = threadIdx.x;
    const int lane = tid & 63;
    const int wave = tid >> 6;

    int zb = bzi, kc = 0;
    if constexpr (EPI == 2) { kc = zb & 1; zb >>= 1; }
    const long long m0 = (long long)bxi * 128;
    const long long n0 = (long long)byi * BN;
    const bf16* Ab = A + (long long)zb * aBatch + (EPI == 2 ? (long long)kc * 2048 : 0);
    const bf16* Bb = Bt + (long long)zb * bBatch + (EPI == 2 ? (long long)kc * 2048 : 0);

    const int wm = (wave & 1) * 64;
    const int wn = (wave >> 1) * (BN / 2);
    const int fm = lane & 15;
    const int q4 = lane >> 4;

    f32x4 acc[4][JN];
    #pragma unroll
    for (int i = 0; i < 4; ++i)
        #pragma unroll
        for (int j = 0; j < JN; ++j)
            acc[i][j] = (f32x4){0.f, 0.f, 0.f, 0.f};

    const int srow = tid >> 3;
    const int schunk = (tid & 7) ^ (srow & 7);

    for (int k0 = 0; k0 < K; k0 += 64) {
        const int kA = k0 + schunk * 8;
        const int kB = (k0 & bkmask) + schunk * 8;
        #pragma unroll
        for (int cb = 0; cb < 4; ++cb) {
            const bf16* g = Ab + (m0 + cb * 32 + srow) * (long long)lda + kA;
            __builtin_amdgcn_global_load_lds((const __attribute__((address_space(1))) void*)g,
                                             (__attribute__((address_space(3))) void*)&As[cb * 2048 + tid * 8], 16, 0, 0);
        }
        #pragma unroll
        for (int cb = 0; cb < BN / 32; ++cb) {
            const bf16* g = Bb + (n0 + cb * 32 + srow) * (long long)ldb + kB;
            __builtin_amdgcn_global_load_lds((const __attribute__((address_space(1))) void*)g,
                                             (__attribute__((address_space(3))) void*)&Bs[cb * 2048 + tid * 8], 16, 0, 0);
        }
        __syncthreads();
        #pragma unroll
        for (int kcc = 0; kcc < 2; ++kcc) {
            bf16x8 fa[4], fb[JN];
            #pragma unroll
            for (int i = 0; i < 4; ++i) {
                const int row = wm + i * 16 + fm;
                const int sw = ((kcc * 4 + q4) ^ (fm & 7)) * 8;
                fa[i] = *(const bf16x8*)&As[row * 64 + sw];
            }
            #pragma unroll
            for (int j = 0; j < JN; ++j) {
                const int row = wn + j * 16 + fm;
                const int sw = ((kcc * 4 + q4) ^ (fm & 7)) * 8;
                fb[j] = *(const bf16x8*)&Bs[row * 64 + sw];
            }
            #pragma unroll
            for (int i = 0; i < 4; ++i)
                #pragma unroll
                for (int j = 0; j < JN; ++j)
                    acc[i][j] = __builtin_amdgcn_mfma_f32_16x16x32_bf16(fa[i], fb[j], acc[i][j], 0, 0, 0);
        }
        __syncthreads();
    }

    // EPI 2: reduce 64 lsum partials -> lrow = 1/l, in the now-dead As space.
    float* lrow = (float*)(smem + 1024);
    if constexpr (EPI == 2) {
        float* lscr = (float*)smem;               // 1024 B
        const float* lsb = lsum + (long long)zb * lsumBatch + m0;
        const int row = tid & 127, h = tid >> 7;
        float s = 0.f;
        #pragma unroll
        for (int p = 0; p < 32; ++p)
            s += lsb[(long long)(h * 32 + p) * SEQ + row];
        lscr[tid] = s;
        __syncthreads();
        if (tid < 128) lrow[tid] = 1.f / (lscr[tid] + lscr[tid + 128]);
        __syncthreads();
    }

    // C/D layout: col = lane&15, row = (lane>>4)*4 + reg  [verified m89/m91]
    const int col = lane & 15;
    const int rowb = (lane >> 4) * 4;

    if constexpr (EPI == 1) {
        bf16* Pb = (bf16*)Cout + (long long)zb * cBatch;
        float* lsw = lsum + (long long)zb * lsumBatch
                   + ((long long)byi * 2 + (wave >> 1)) * SEQ;
        #pragma unroll
        for (int i = 0; i < 4; ++i) {
            float rs[4] = {0.f, 0.f, 0.f, 0.f};
            long long mg = m0 + wm + i * 16 + rowb;
            #pragma unroll
            for (int j = 0; j < JN; ++j) {
                long long ng = n0 + wn + j * 16 + col;
                #pragma unroll
                for (int r = 0; r < 4; ++r) {
                    float e = __expf(acc[i][j][r] * scale);
                    rs[r] += e;
                    Pb[(mg + r) * (long long)ldc + ng] = (bf16)e;
                }
            }
            #pragma unroll
            for (int r = 0; r < 4; ++r) {
                rs[r] += __shfl_xor(rs[r], 1);
                rs[r] += __shfl_xor(rs[r], 2);
                rs[r] += __shfl_xor(rs[r], 4);
                rs[r] += __shfl_xor(rs[r], 8);
            }
            if (col == 0) {
                #pragma unroll
                for (int r = 0; r < 4; ++r) lsw[mg + r] = rs[r];
            }
        }
    } else {
        #pragma unroll
        for (int i = 0; i < 4; ++i) {
            #pragma unroll
            for (int j = 0; j < JN; ++j) {
                long long mg = m0 + wm + i * 16 + rowb;
                long long ng = n0 + wn + j * 16 + col;
                #pragma unroll
                for (int r = 0; r < 4; ++r) {
                    float v = acc[i][j][r];
                    long long m = mg + r;
                    if constexpr (EPI == 0) {
                        ((bf16*)Cout)[m * (long long)ldc + ng] = (bf16)(v + bias[ng]);
                    } else if constexpr (EPI == 2) {
                        float inv = lrow[(int)(m - m0)];
                        ((bf16*)Cout)[(long long)zb * cBatch + m * (long long)ldc
                                      + kc * 512 + ng] = (bf16)(v * inv);
                    } else {
                        ((float*)Cout)[m * (long long)ldc + ng] =
                            v + bias[ng] + resid[m * CCH + ng];
                    }
                }
            }
        }
    }
}

// ---------------------------------------------------------------------------
struct FusedArgs {
    const float *x, *gamma, *beta, *Wq, *bq, *Wk, *bk, *Wv, *bv, *Wp, *bp;
    float* out;
    float* statsP; float* biasQKV; bf16* WqkvT; bf16* WpT; bf16* xn;
    float* lsum; bf16* qkv; bf16* o2; bf16* vT; bf16* P;
    unsigned* bar;
};

__global__ __launch_bounds__(256, 4) void persistent(FusedArgs a) {
    __shared__ __align__(16) char smem[SMEM_BYTES];
    const int nb = PGRID;
    const float scale = 0.044194173824159216f;   // 1/sqrt(512)

    // Phase 1: GN stats partials + weight transposes + bias pack (1537 units)
    for (int w = blockIdx.x; w < 1537; w += nb)
        prep_unit(smem, w, a.x, a.Wq, a.Wk, a.Wv, a.Wp, a.bq, a.bk, a.bv,
                  a.statsP, a.WqkvT, a.WpT, a.biasQKV);
    grid_bar(a.bar, 0);

    // Phase 2: normalize + cast (4096 units)
    gn_table(smem, a.statsP);
    for (int w = blockIdx.x; w < 4096; w += nb)
        gn_unit(smem, w, a.x, a.gamma, a.beta, a.xn);
    grid_bar(a.bar, 1);

    // Phase 3: qkv = xn @ WqkvT^T + bias (768 tiles: M=8192, N=1536, K=512)
    // R9 map: XCD (w&7) owns 8 M-strips x 12 N-tiles; per-XCD working set
    // A 8x128KB + B 1.5MB = 2.5MB <= 4MB L2.
    for (int w = blockIdx.x; w < 768; w += nb) {
        int l = w >> 3;                       // [0,96)
        gemm2_body<0, 128>(smem, (w & 7) * 8 + l / 12, l % 12, 0,
                           a.xn, 0, CCH, a.WqkvT, 0, CCH, a.qkv, 0, 1536,
                           CCH, NOMASK, 1.f, a.biasQKV, nullptr, nullptr, 0);
    }
    grid_bar(a.bar, 2);

    // Phase 4: v transpose (1024) + P = exp(scale*qk^T) + lsum partials (2048)
    // R9 map (QK): per batch, XCD (r&7) owns 4 q-rows x 32 k-cols; q strips
    // 1MB L2-resident, each k-strip shared by 4 lockstep co-resident blocks.
    for (int w = blockIdx.x; w < 3072; w += nb) {
        if (w < 1024) {
            int b = w >> 9, r = w & 511;
            vtrans_unit(smem, a.qkv, a.vT, b, (r >> 3) * 64, (r & 7) * 64);
        } else {
            int u = w - 1024;
            int bz = u >> 10, r = u & 1023;
            int l = r >> 3;                   // [0,128)
            gemm2_body<1, 128>(smem, (r & 7) * 4 + (l >> 5), l & 31, bz,
                               a.qkv, (long long)SEQ * 1536, 1536,
                               a.qkv + 512, (long long)SEQ * 1536, 1536,
                               a.P, (long long)SEQ * SEQ, SEQ,
                               CCH, NOMASK, scale, nullptr, nullptr,
                               a.lsum, 64LL * SEQ);
        }
    }
    grid_bar(a.bar, 3);

    // Phase 5: o2 = (P/l) @ v, BN=64, split-K=2 side-by-side (1024 tiles)
    // R9 map: strip-grouped — the 8 N-tiles sharing one 0.5MB P strip land on
    // 8 adjacent blocks of XCD (w&7); P read amp 8x collapses into L2.
    for (int w = blockIdx.x; w < 1024; w += nb) {
        int l = w >> 3;                       // [0,128)
        int S = (w & 7) * 16 + (l >> 3);      // strip id [0,128)
        gemm2_body<2, 64>(smem, S & 31, l & 7, S >> 5,
                          a.P, (long long)SEQ * SEQ, SEQ,
                          a.vT, (long long)CCH * SEQ, SEQ,
                          a.o2, (long long)SEQ * 1024, 1024,
                          2048, NOMASK, 1.f, nullptr, nullptr,
                          a.lsum, 64LL * SEQ);
    }
    grid_bar(a.bar, 4);

    // Phase 6: out = [o2_k0 o2_k1] @ [Wp;Wp] + bp + x (512 tiles, K=1024,
    // B k wrapped mod 512)
    // R9 map: XCD (w&7) owns 8 o2-strips x 8 N-tiles; A 2MB + WpT 0.5MB in L2.
    for (int w = blockIdx.x; w < 512; w += nb) {
        int l = w >> 3;                       // [0,64)
        gemm2_body<3, 64>(smem, (w & 7) * 8 + (l >> 3), l & 7, 0,
                          a.o2, 0, 1024, a.WpT, 0, CCH, a.out, 0, CCH,
                          1024, 511, 1.f, a.bp, a.x, nullptr, 0);
    }
}

// ---------------------------------------------------------------------------
// Fallback multi-dispatch kernels (R5 schedule, proven at 220.8us).
__global__ __launch_bounds__(256) void k_prep(
    const float* x, const float* Wq, const float* Wk, const float* Wv,
    const float* Wp, const float* bq, const float* bk, const float* bv,
    float* statsP, bf16* WqkvT, bf16* WpT, float* biasQKV) {
    __shared__ __align__(16) char smem[4352];
    prep_unit(smem, blockIdx.x, x, Wq, Wk, Wv, Wp, bq, bk, bv,
              statsP, WqkvT, WpT, biasQKV);
}

__global__ __launch_bounds__(256) void k_gn(
    const float* x, const float* statsP, const float* gamma,
    const float* beta, bf16* xn) {
    __shared__ __align__(16) char smem[512];
    gn_table(smem, statsP);
    gn_unit(smem, blockIdx.x, x, statsP == nullptr ? gamma : gamma, beta, xn);
}

template <int EPI, int BN>
__global__ __launch_bounds__(256, 2) void k_gemm2(
    const bf16* A, long long aBatch, int lda,
    const bf16* Bt, long long bBatch, int ldb,
    void* Cout, long long cBatch, int ldc,
    int K, int bkmask, float scale,
    const float* bias, const float* resid,
    float* lsum, long long lsumBatch) {
    __shared__ __align__(16) char smem[SMEM_BYTES];
    gemm2_body<EPI, BN>(smem, blockIdx.x, blockIdx.y, blockIdx.z,
                        A, aBatch, lda, Bt, bBatch, ldb, Cout, cBatch, ldc,
                        K, bkmask, scale, bias, resid, lsum, lsumBatch);
}

__global__ __launch_bounds__(256, 2) void k_qk_vtrans(
    const bf16* qkv, bf16* vT, bf16* P, float* lsum, float scale,
    int vtBlocks, long long qkBatch, long long pBatch, long long lsumBatch) {
    __shared__ __align__(16) char smem[SMEM_BYTES];
    const int bid = blockIdx.x;
    if (bid < vtBlocks) {
        int b = bid >> 9, r = bid & 511;
        vtrans_unit(smem, qkv, vT, b, (r >> 3) * 64, (r & 7) * 64);
    } else {
        int q = bid - vtBlocks;
        int bz = q >> 10, r = q & 1023;
        gemm2_body<1, 128>(smem, r >> 5, r & 31, bz,
                           qkv, qkBatch, 1536, qkv + 512, qkBatch, 1536,
                           P, pBatch, SEQ, CCH, NOMASK, scale,
                           nullptr, nullptr, lsum, lsumBatch);
    }
}

// ---------------------------------------------------------------------------
extern "C" void kernel_launch(void* const* d_in, const int* in_sizes, int n_in,
                              void* d_out, int out_size, void* d_ws, size_t ws_size,
                              hipStream_t stream) {
    const float* x     = (const float*)d_in[0];
    const float* gamma = (const float*)d_in[1];
    const float* beta  = (const float*)d_in[2];
    const float* Wq    = (const float*)d_in[3];
    const float* bq    = (const float*)d_in[4];
    const float* Wk    = (const float*)d_in[5];
    const float* bk    = (const float*)d_in[6];
    const float* Wv    = (const float*)d_in[7];
    const float* bv    = (const float*)d_in[8];
    const float* Wp    = (const float*)d_in[9];
    const float* bp    = (const float*)d_in[10];
    float* out = (float*)d_out;

    // Workspace (aliased; lifetimes: xn dead after QKV, q/k dead after QK)
    constexpr size_t OFF_STATS = 0;          // 4 KB (statsP partials, 1024 f32)
    constexpr size_t OFF_BIAS  = 4096;       // 6 KB
    constexpr size_t OFF_BAR   = 10240;      // 64 B grid-barrier counters
    constexpr size_t OFF_WQKVT = 12288;      // 1.57 MB
    constexpr size_t OFF_WPT   = 1585152;    // 0.5 MB [512][512]
    constexpr size_t OFF_XN    = 2109440;    // 8.39 MB; dead after QKV ->
    constexpr size_t OFF_LSUM  = OFF_XN;     //   2.10 MB [2][64][4096] f32
    constexpr size_t OFF_QKV   = 10498048;   // 25.17 MB; q,k dead after QK ->
    constexpr size_t OFF_O2    = OFF_QKV;    //   16.78 MB [8192][1024] bf16
    constexpr size_t OFF_VT    = 35663872;   // 8.39 MB [2][512][4096]
    constexpr size_t OFF_P     = 44052480;   // 67.1 MB (full) / 33.6 MB (per-batch)
    constexpr size_t NEED_FULL = OFF_P + (size_t)NBAT * SEQ * SEQ * 2;

    char* ws = (char*)d_ws;
    float* statsP  = (float*)(ws + OFF_STATS);
    float* biasQKV = (float*)(ws + OFF_BIAS);
    unsigned* bar  = (unsigned*)(ws + OFF_BAR);
    bf16*  WqkvT   = (bf16*)(ws + OFF_WQKVT);
    bf16*  WpT     = (bf16*)(ws + OFF_WPT);
    bf16*  xn      = (bf16*)(ws + OFF_XN);
    float* lsum    = (float*)(ws + OFF_LSUM);
    bf16*  qkv     = (bf16*)(ws + OFF_QKV);
    bf16*  o2      = (bf16*)(ws + OFF_O2);
    bf16*  vT      = (bf16*)(ws + OFF_VT);
    bf16*  P       = (bf16*)(ws + OFF_P);

    const float scale = 0.044194173824159216f;  // 1/sqrt(512)
    const bool full = ws_size >= NEED_FULL;

    // Use the persistent kernel only if the runtime confirms >=4 blocks/CU
    // co-residency (guards against VGPR/LDS surprises -> barrier deadlock).
    bool usePersist = false;
    if (full) {
        int occ = 0;
        hipError_t oe = hipOccupancyMaxActiveBlocksPerMultiprocessor(
            &occ, (const void*)persistent, 256, 0);
        usePersist = (oe == hipSuccess && occ >= 4);
        if (!usePersist) (void)hipGetLastError();
    }

    if (usePersist) {
        hipMemsetAsync(ws + OFF_BAR, 0, 64, stream);   // zero barrier counters
        FusedArgs a{x, gamma, beta, Wq, bq, Wk, bk, Wv, bv, Wp, bp, out,
                    statsP, biasQKV, WqkvT, WpT, xn, lsum, qkv, o2, vT, P, bar};
        persistent<<<PGRID, 256, 0, stream>>>(a);
    } else {
        // R5's proven 7-dispatch schedule.
        k_prep<<<1537, 256, 0, stream>>>(x, Wq, Wk, Wv, Wp, bq, bk, bv,
                                         statsP, WqkvT, WpT, biasQKV);
        k_gn<<<4096, 256, 0, stream>>>(x, statsP, gamma, beta, xn);
        k_gemm2<0, 128><<<dim3(64, 12, 1), 256, 0, stream>>>(
            xn, 0, CCH, WqkvT, 0, CCH, qkv, 0, 1536,
            CCH, NOMASK, 1.f, biasQKV, nullptr, nullptr, 0);
        if (full) {
            k_qk_vtrans<<<3072, 256, 0, stream>>>(
                qkv, vT, P, lsum, scale, 1024,
                (long long)SEQ * 1536, (long long)SEQ * SEQ, 64LL * SEQ);
            k_gemm2<2, 128><<<dim3(32, 4, NBAT * 2), 256, 0, stream>>>(
                P, (long long)SEQ * SEQ, SEQ, vT, (long long)CCH * SEQ, SEQ,
                o2, (long long)SEQ * 1024, 1024,
                2048, NOMASK, 1.f, nullptr, nullptr, lsum, 64LL * SEQ);
        } else {
            for (int b = 0; b < NBAT; ++b) {
                const bf16* qb = qkv + (long long)b * SEQ * 1536;
                k_qk_vtrans<<<1536, 256, 0, stream>>>(
                    qb, vT + (long long)b * CCH * SEQ, P,
                    lsum + (long long)b * 64 * SEQ, scale, 512, 0, 0, 0);
                k_gemm2<2, 128><<<dim3(32, 4, 2), 256, 0, stream>>>(
                    P, 0, SEQ, vT + (long long)b * CCH * SEQ, 0, SEQ,
                    o2 + (long long)b * SEQ * 1024, 0, 1024,
                    2048, NOMASK, 1.f, nullptr, nullptr,
                    lsum + (long long)b * 64 * SEQ, 0);
            }
        }
        k_gemm2<3, 64><<<dim3(64, 8, 1), 256, 0, stream>>>(
            o2, 0, 1024, WpT, 0, CCH, out, 0, CCH,
            1024, 511, 1.f, bp, x, nullptr, 0);
    }
}